// Round 4
// baseline (217.209 us; speedup 1.0000x reference)
//
#include <hip/hip_runtime.h>
#include <math.h>

#define NB     16      // batches
#define NP     4096    // points per cloud (N == M)
#define BLK    256     // 4 waves; wave w handles y-quarter w of each chunk
#define XPB    64      // x-points per block (one per lane)
#define CHUNK  1024    // y-points staged in LDS per chunk (16 KB)
#define NCHUNK (NP / CHUNK)   // 4
#define YQ     (CHUNK / 4)    // 256 y per wave per chunk

// One block = 64 x-points vs ALL of M. Inner loop: 4 VALU/pair
// (3 FMA accumulating dot onto -0.5*||y||^2 bias + 1 fmax; min over d ==
// max over m since d/2 = 0.5*||x||^2 - m). Each wave covers a y-quarter;
// quarters combine via LDS max at the end, then sqrt + wave reduce + one
// atomicAdd per block. No workspace, no cross-block min.
__global__ __launch_bounds__(BLK, 8) void chamfer_kernel(
    const float* __restrict__ A1, const float* __restrict__ A2,
    float* __restrict__ out)
{
    __shared__ float4 sy[CHUNK];   // 16 KB; 8 blocks/CU -> 128 KB of 160
    const int b   = blockIdx.x;    // batch
    const int xc  = blockIdx.y;    // x-chunk (NP/XPB = 64)
    const int dir = blockIdx.z;    // direction
    const float* X = dir ? A2 : A1;
    const float* Y = dir ? A1 : A2;

    const int tid  = threadIdx.x;
    const int lane = tid & 63;
    const int w    = tid >> 6;

    // My x-point (coalesced 12 B/lane).
    const int xn = xc * XPB + lane;
    const float* Xb = X + ((size_t)b * NP + xn) * 3;
    const float px = Xb[0], py = Xb[1], pz = Xb[2];
    const float ax = 0.5f * (px * px + py * py + pz * pz);

    const float* Yb = Y + (size_t)b * NP * 3;
    float mx = -3.3e38f;

    for (int c = 0; c < NCHUNK; ++c) {
        __syncthreads();   // previous chunk fully consumed
        for (int i = tid; i < CHUNK; i += BLK) {
            const float* yp = Yb + (size_t)(c * CHUNK + i) * 3;
            const float yx = yp[0], yy = yp[1], yz = yp[2];
            sy[i] = make_float4(yx, yy, yz, -0.5f * (yx * yx + yy * yy + yz * yz));
        }
        __syncthreads();

        const float4* syq = sy + w * YQ;   // this wave's quarter
        #pragma unroll 4
        for (int j = 0; j < YQ; ++j) {
            const float4 y = syq[j];       // wave-uniform LDS broadcast
            float m = fmaf(px, y.x, y.w);
            m = fmaf(py, y.y, m);
            m = fmaf(pz, y.z, m);
            mx = fmaxf(mx, m);
        }
    }

    // Combine the 4 wave-quarters, then sqrt + reduce + one atomic per block.
    __syncthreads();
    float* smx = (float*)sy;   // reuse LDS
    smx[tid] = mx;
    __syncthreads();
    if (tid < 64) {
        const float mc = fmaxf(fmaxf(smx[tid], smx[tid + 64]),
                               fmaxf(smx[tid + 128], smx[tid + 192]));
        const float e = fmaxf(ax - mc, 0.0f);   // = d_min / 2
        float v = sqrtf(2.0f * e);
        #pragma unroll
        for (int off = 32; off > 0; off >>= 1)
            v += __shfl_down(v, off, 64);
        if (lane == 0)
            // out = (sum1+sum2) * 1000 / (2 * NB * NP); 1000/131072 exact.
            atomicAdd(out, v * 0.00762939453125f);
    }
}

extern "C" void kernel_launch(void* const* d_in, const int* in_sizes, int n_in,
                              void* d_out, int out_size, void* d_ws, size_t ws_size,
                              hipStream_t stream)
{
    const float* a1 = (const float*)d_in[0];  // [NB, NP, 3] fp32
    const float* a2 = (const float*)d_in[1];  // [NB, NP, 3] fp32
    float* out = (float*)d_out;

    hipMemsetAsync(out, 0, sizeof(float), stream);   // d_out is poisoned 0xAA

    dim3 grid(NB, NP / XPB, 2);   // 16 x 64 x 2 = 2048 blocks = 8/CU
    chamfer_kernel<<<grid, BLK, 0, stream>>>(a1, a2, out);
}

// Round 5
// 127.429 us; speedup vs baseline: 1.7046x; 1.7046x over previous
//
#include <hip/hip_runtime.h>
#include <math.h>

#define NB     16      // batches
#define NP     4096    // points per cloud (N == M)
#define BLK    256     // 4 waves
#define ILP    8       // x-points per lane -> one LDS read feeds 32 VALU ops
#define XPB    (64 * ILP)     // 512 x-points per block (all waves hold all of them)
#define CHUNK  1024    // y-points staged in LDS per chunk (16 KB)
#define NCHUNK (NP / CHUNK)   // 4
#define YQ     (CHUNK / 4)    // per-wave y quarter per chunk

// LDS-pipe math (R4 post-mortem): broadcast ds_read_b128 costs ~13 cyc of the
// per-CU LDS pipe. At ILP=1 that was 6x oversubscribed vs 4 VALU/pair. Here
// one ds_read feeds 8 x-points (32 VALU) -> LDS ~17 us/CU < VALU ~27 us.
// Inner loop stays 4 VALU/pair: 3 FMA (dot onto -0.5||y||^2 bias in .w) + fmax;
// d/2 = 0.5||x||^2 - m, so min-d == max-m; subtract/clamp deferred to epilogue.
__global__ __launch_bounds__(BLK, 2) void chamfer_kernel(
    const float* __restrict__ A1, const float* __restrict__ A2,
    float* __restrict__ out)
{
    __shared__ float4 sy[CHUNK];   // 16 KB
    const int b   = blockIdx.x;    // batch
    const int xc  = blockIdx.y;    // x-chunk (NP/XPB = 8)
    const int dir = blockIdx.z;    // direction
    const float* X = dir ? A2 : A1;
    const float* Y = dir ? A1 : A2;

    const int tid  = threadIdx.x;
    const int lane = tid & 63;
    const int w    = tid >> 6;

    // My 8 x-points (lanes contiguous within each p -> coalesced 12 B/lane).
    const float* Xb = X + ((size_t)b * NP + xc * XPB) * 3;
    float px[ILP], py[ILP], pz[ILP], ax[ILP], mx[ILP];
    #pragma unroll
    for (int p = 0; p < ILP; ++p) {
        const int n = p * 64 + lane;
        px[p] = Xb[n * 3 + 0];
        py[p] = Xb[n * 3 + 1];
        pz[p] = Xb[n * 3 + 2];
        ax[p] = 0.5f * (px[p] * px[p] + py[p] * py[p] + pz[p] * pz[p]);
        mx[p] = -3.3e38f;
    }

    const float* Yb = Y + (size_t)b * NP * 3;
    for (int c = 0; c < NCHUNK; ++c) {
        __syncthreads();   // previous chunk fully consumed
        for (int i = tid; i < CHUNK; i += BLK) {
            const float* yp = Yb + (size_t)(c * CHUNK + i) * 3;
            const float yx = yp[0], yy = yp[1], yz = yp[2];
            sy[i] = make_float4(yx, yy, yz, -0.5f * (yx * yx + yy * yy + yz * yz));
        }
        __syncthreads();

        const float4* syq = sy + w * YQ;   // this wave's quarter
        #pragma unroll 4
        for (int j = 0; j < YQ; ++j) {
            const float4 y = syq[j];       // one broadcast b128 per 32 VALU ops
            #pragma unroll
            for (int p = 0; p < ILP; ++p) {
                float m = fmaf(pz[p], y.z, y.w);
                m = fmaf(py[p], y.y, m);
                m = fmaf(px[p], y.x, m);
                mx[p] = fmaxf(mx[p], m);
            }
        }
    }

    // Combine the 4 wave-partials per x-slot, then sqrt + block sum + 1 atomic.
    __syncthreads();
    float* sbuf = (float*)sy;         // [4][XPB] wave maxes + [XPB] ax = 10 KB
    float* sax  = sbuf + 4 * XPB;
    #pragma unroll
    for (int p = 0; p < ILP; ++p) {
        sbuf[w * XPB + p * 64 + lane] = mx[p];
        if (w == 0) sax[p * 64 + lane] = ax[p];
    }
    __syncthreads();

    float v = 0.0f;
    #pragma unroll
    for (int s = tid; s < XPB; s += BLK) {
        const float mc = fmaxf(fmaxf(sbuf[s], sbuf[XPB + s]),
                               fmaxf(sbuf[2 * XPB + s], sbuf[3 * XPB + s]));
        const float e = fmaxf(sax[s] - mc, 0.0f);   // = d_min / 2
        v += sqrtf(2.0f * e);
    }
    #pragma unroll
    for (int off = 32; off > 0; off >>= 1)
        v += __shfl_down(v, off, 64);

    __shared__ float ws[4];
    if (lane == 0) ws[w] = v;
    __syncthreads();
    if (tid == 0) {
        const float s = (ws[0] + ws[1]) + (ws[2] + ws[3]);
        // out = (sum1+sum2) * 1000 / (2 * NB * NP); 1000/131072 exact in fp32.
        atomicAdd(out, s * 0.00762939453125f);
    }
}

extern "C" void kernel_launch(void* const* d_in, const int* in_sizes, int n_in,
                              void* d_out, int out_size, void* d_ws, size_t ws_size,
                              hipStream_t stream)
{
    const float* a1 = (const float*)d_in[0];  // [NB, NP, 3] fp32
    const float* a2 = (const float*)d_in[1];  // [NB, NP, 3] fp32
    float* out = (float*)d_out;

    hipMemsetAsync(out, 0, sizeof(float), stream);   // d_out is poisoned 0xAA

    dim3 grid(NB, NP / XPB, 2);   // 16 x 8 x 2 = 256 blocks
    chamfer_kernel<<<grid, BLK, 0, stream>>>(a1, a2, out);
}

// Round 6
// 97.068 us; speedup vs baseline: 2.2377x; 1.3128x over previous
//
#include <hip/hip_runtime.h>
#include <math.h>

#define NB     16      // batches
#define NP     4096    // points per cloud (N == M)
#define BLK    1024    // 16 waves; wave w handles y-sixteenth of each chunk
#define NWAVE  16
#define ILP    8       // x-points per lane -> one LDS read feeds 32 VALU ops
#define XPB    (64 * ILP)     // 512 x-points per block (every wave holds all)
#define CHUNK  1024    // y-points staged in LDS per chunk (16 KB)
#define NCHUNK (NP / CHUNK)   // 4
#define YQ     (CHUNK / NWAVE)  // 64 y per wave per chunk

// R5 post-mortem: structure was right (LDS 22us < VALU 27us ideal) but 1
// wave/SIMD left 42% VALU idle to staging latency + barrier edges. Same
// 2-node fused graph, now 16 waves/block (4/SIMD) for latency hiding.
// Inner loop: 4 VALU/pair -- 3 FMA (dot accumulated onto -0.5||y||^2 bias
// in .w) + fmax; d/2 = 0.5||x||^2 - m so min-d == max-m, subtract/clamp
// deferred to the epilogue. One broadcast ds_read_b128 per 32 VALU ops.
__global__ __launch_bounds__(BLK, 4) void chamfer_kernel(
    const float* __restrict__ A1, const float* __restrict__ A2,
    float* __restrict__ out)
{
    __shared__ float4 sy[CHUNK];   // 16 KB; 1 block/CU
    const int b   = blockIdx.x;    // batch
    const int xc  = blockIdx.y;    // x-chunk (NP/XPB = 8)
    const int dir = blockIdx.z;    // direction
    const float* X = dir ? A2 : A1;
    const float* Y = dir ? A1 : A2;

    const int tid  = threadIdx.x;
    const int lane = tid & 63;
    const int w    = tid >> 6;     // 0..15

    // My 8 x-points (lanes contiguous within each p -> coalesced 12 B/lane).
    const float* Xb = X + ((size_t)b * NP + xc * XPB) * 3;
    float px[ILP], py[ILP], pz[ILP], ax[ILP], mx[ILP];
    #pragma unroll
    for (int p = 0; p < ILP; ++p) {
        const int n = p * 64 + lane;
        px[p] = Xb[n * 3 + 0];
        py[p] = Xb[n * 3 + 1];
        pz[p] = Xb[n * 3 + 2];
        ax[p] = 0.5f * (px[p] * px[p] + py[p] * py[p] + pz[p] * pz[p]);
        mx[p] = -3.3e38f;
    }

    const float* Yb = Y + (size_t)b * NP * 3;
    for (int c = 0; c < NCHUNK; ++c) {
        __syncthreads();   // previous chunk fully consumed
        {
            const int i = tid;  // 1024 threads stage 1024 y: 12 KB contiguous
            const float* yp = Yb + (size_t)(c * CHUNK + i) * 3;
            const float yx = yp[0], yy = yp[1], yz = yp[2];
            sy[i] = make_float4(yx, yy, yz, -0.5f * (yx * yx + yy * yy + yz * yz));
        }
        __syncthreads();

        const float4* syq = sy + w * YQ;   // this wave's sixteenth
        #pragma unroll 4
        for (int j = 0; j < YQ; ++j) {
            const float4 y = syq[j];       // one broadcast b128 per 32 VALU ops
            #pragma unroll
            for (int p = 0; p < ILP; ++p) {
                float m = fmaf(pz[p], y.z, y.w);
                m = fmaf(py[p], y.y, m);
                m = fmaf(px[p], y.x, m);
                mx[p] = fmaxf(mx[p], m);
            }
        }
    }

    // Tree-combine 16 wave-partials (16 KB LDS per round, reusing sy).
    __syncthreads();
    float* sbuf = (float*)sy;
    for (int half = NWAVE / 2; half >= 1; half >>= 1) {
        if (w >= half && w < 2 * half) {
            #pragma unroll
            for (int p = 0; p < ILP; ++p)
                sbuf[(w - half) * XPB + p * 64 + lane] = mx[p];
        }
        __syncthreads();
        if (w < half) {
            #pragma unroll
            for (int p = 0; p < ILP; ++p)
                mx[p] = fmaxf(mx[p], sbuf[w * XPB + p * 64 + lane]);
        }
        __syncthreads();
    }

    if (w == 0) {   // wave 0 holds the full max and its own ax copy
        float v = 0.0f;
        #pragma unroll
        for (int p = 0; p < ILP; ++p) {
            const float e = fmaxf(ax[p] - mx[p], 0.0f);   // = d_min / 2
            v += sqrtf(2.0f * e);
        }
        #pragma unroll
        for (int off = 32; off > 0; off >>= 1)
            v += __shfl_down(v, off, 64);
        if (lane == 0)
            // out = (sum1+sum2) * 1000 / (2 * NB * NP); 1000/131072 exact.
            atomicAdd(out, v * 0.00762939453125f);
    }
}

extern "C" void kernel_launch(void* const* d_in, const int* in_sizes, int n_in,
                              void* d_out, int out_size, void* d_ws, size_t ws_size,
                              hipStream_t stream)
{
    const float* a1 = (const float*)d_in[0];  // [NB, NP, 3] fp32
    const float* a2 = (const float*)d_in[1];  // [NB, NP, 3] fp32
    float* out = (float*)d_out;

    hipMemsetAsync(out, 0, sizeof(float), stream);   // d_out is poisoned 0xAA

    dim3 grid(NB, NP / XPB, 2);   // 16 x 8 x 2 = 256 blocks of 1024 threads
    chamfer_kernel<<<grid, BLK, 0, stream>>>(a1, a2, out);
}